// Round 17
// baseline (685.644 us; speedup 1.0000x reference)
//
#include <hip/hip_runtime.h>
#include <hip/hip_fp16.h>

#define N_NODES 50000
#define HID 128
#define NH (N_NODES * HID)      // 6,400,000 elems per [N,HID] buffer
#define NE 1600000

#define EPB   8192              // edges per K1/K3 block
#define NBLK1 196               // ceil(NE / EPB)
#define NBUK  391               // ceil(N_NODES / 128) row buckets (128 rows each)
#define TBL   (NBUK * NBLK1)    // 76,636 scan table entries per op
#define SB    ((TBL + 255) / 256)  // 300 scan blocks per op
#define PTRW  (N_NODES + 2)     // words per rowptr array

#define TROWS 128               // rows per tail block
#define TPAD  136               // fp16 row pitch in LDS

typedef _Float16 f16x8 __attribute__((ext_vector_type(8)));
typedef float    f32x4 __attribute__((ext_vector_type(4)));

// ---- fp16 helpers (RNE) ----
__device__ __forceinline__ float h2f(unsigned short u) {
    __half_raw r; r.x = u;
    __half h = r;
    return __half2float(h);
}
__device__ __forceinline__ unsigned short f2h(float f) {
    __half h = __float2half_rn(f);
    __half_raw r = h;
    return r.x;
}

// ===========================================================================
// K1 (batched 4 ops): per-block LDS histogram only (no rank materialized —
// k3 re-derives positions via LDS atomicAdd on the scanned bases).
// ===========================================================================
__global__ __launch_bounds__(256) void k1_hist4(
    const int* __restrict__ r0, const int* __restrict__ r1,
    const int* __restrict__ r2, const int* __restrict__ r3,
    int* __restrict__ table4)
{
    __shared__ int h[NBUK];
    int o = blockIdx.y, b = blockIdx.x, t = threadIdx.x;
    const int* rows = o == 0 ? r0 : o == 1 ? r1 : o == 2 ? r2 : r3;
    int* table = table4 + (size_t)o * TBL;

    for (int i = t; i < NBUK; i += 256) h[i] = 0;
    __syncthreads();
    int e0 = b * EPB;
    int e1 = min(e0 + EPB, NE);
    for (int e = e0 + t; e < e1; e += 256)
        atomicAdd(&h[rows[e] >> 7], 1);
    __syncthreads();
    for (int i = t; i < NBUK; i += 256) table[i * NBLK1 + b] = h[i];
}

// ===========================================================================
// S1/S2/S3 (batched): hierarchical exclusive scan of each op's table
// ===========================================================================
__global__ __launch_bounds__(256) void s1_partial4(
    const int* __restrict__ table4, int* __restrict__ part4)
{
    __shared__ int red[256];
    int o = blockIdx.y, b = blockIdx.x, t = threadIdx.x;
    const int* table = table4 + (size_t)o * TBL;
    int idx = b * 256 + t;
    red[t] = (idx < TBL) ? table[idx] : 0;
    __syncthreads();
    #pragma unroll
    for (int s = 128; s > 0; s >>= 1) {
        if (t < s) red[t] += red[t + s];
        __syncthreads();
    }
    if (t == 0) part4[o * SB + b] = red[0];
}

__global__ __launch_bounds__(1024) void s2_scan4(int* __restrict__ part4)
{
    __shared__ int sh[1024];
    int o = blockIdx.x, t = threadIdx.x;
    int* part = part4 + o * SB;
    sh[t] = (t < SB) ? part[t] : 0;
    __syncthreads();
    for (int off = 1; off < 1024; off <<= 1) {
        int v = (t >= off) ? sh[t - off] : 0;
        __syncthreads();
        sh[t] += v;
        __syncthreads();
    }
    if (t < SB) part[t] = (t == 0) ? 0 : sh[t - 1];
}

__global__ __launch_bounds__(256) void s3_add4(
    int* __restrict__ table4, const int* __restrict__ part4)
{
    __shared__ int sh[256];
    int o = blockIdx.y, b = blockIdx.x, t = threadIdx.x;
    int* table = table4 + (size_t)o * TBL;
    int idx = b * 256 + t;
    int v = (idx < TBL) ? table[idx] : 0;
    sh[t] = v;
    __syncthreads();
    #pragma unroll
    for (int off = 1; off < 256; off <<= 1) {
        int u = (t >= off) ? sh[t - off] : 0;
        __syncthreads();
        sh[t] += u;
        __syncthreads();
    }
    int excl = (t == 0) ? 0 : sh[t - 1];
    if (idx < TBL) table[idx] = part4[o * SB + b] + excl;
}

// ===========================================================================
// K3 (batched): scatter into bucket-partitioned split tmp arrays.
// Position = LDS atomicAdd on the scanned per-(bucket,block) base — any
// permutation within a bucket is a valid sort order, so no rank needed.
// tmp_row: 1B (row&127); tmp_pay: 4B (col<<16 | fp16 val).
// ===========================================================================
__global__ __launch_bounds__(256) void k3_scatter4(
    const int* __restrict__ r0, const int* __restrict__ r1,
    const int* __restrict__ r2, const int* __restrict__ r3,
    const int* __restrict__ c0, const int* __restrict__ c1,
    const int* __restrict__ c2, const int* __restrict__ c3,
    const float* __restrict__ v0, const float* __restrict__ v1,
    const float* __restrict__ v2, const float* __restrict__ v3,
    const int* __restrict__ table4,
    unsigned char* __restrict__ tmp_row4, unsigned* __restrict__ tmp_pay4)
{
    __shared__ int base[NBUK];
    int o = blockIdx.y, b = blockIdx.x, t = threadIdx.x;
    const int*   rows = o == 0 ? r0 : o == 1 ? r1 : o == 2 ? r2 : r3;
    const int*   cols = o == 0 ? c0 : o == 1 ? c1 : o == 2 ? c2 : c3;
    const float* vals = o == 0 ? v0 : o == 1 ? v1 : o == 2 ? v2 : v3;
    const int* table = table4 + (size_t)o * TBL;
    unsigned char* tmp_row = tmp_row4 + (size_t)o * NE;
    unsigned*      tmp_pay = tmp_pay4 + (size_t)o * NE;

    for (int i = t; i < NBUK; i += 256) base[i] = table[i * NBLK1 + b];
    __syncthreads();
    int e0 = b * EPB;
    int e1 = min(e0 + EPB, NE);
    for (int e = e0 + t; e < e1; e += 256) {
        int r = rows[e];
        int pos = atomicAdd(&base[r >> 7], 1);
        tmp_row[pos] = (unsigned char)(r & 127);
        tmp_pay[pos] = ((unsigned)cols[e] << 16) | (unsigned)f2h(vals[e]);
    }
}

// ===========================================================================
// K4 (batched): per-bucket fine sort -> packed pairs (4B) + rowptr.
// Count pass reads 1B rows only; scatter pass reads rows + payload.
// ===========================================================================
__global__ __launch_bounds__(256) void k4_fine4(
    const int* __restrict__ table4, const unsigned char* __restrict__ tmp_row4,
    const unsigned* __restrict__ tmp_pay4,
    unsigned* __restrict__ pairs4, int* __restrict__ ptr4)
{
    __shared__ int cnt[128];
    __shared__ int sh[256];
    __shared__ int nxt[128];
    int o = blockIdx.y, k = blockIdx.x, t = threadIdx.x;
    const int* table = table4 + (size_t)o * TBL;
    const unsigned char* tmp_row = tmp_row4 + (size_t)o * NE;
    const unsigned*      tmp_pay = tmp_pay4 + (size_t)o * NE;
    unsigned* pairs = pairs4 + (size_t)o * NE;
    int* rowptr = ptr4 + (size_t)o * PTRW;

    if (t < 128) cnt[t] = 0;
    __syncthreads();
    int base = table[k * NBLK1];
    int end  = (k == NBUK - 1) ? NE : table[(k + 1) * NBLK1];
    for (int e = base + t; e < end; e += 256)
        atomicAdd(&cnt[tmp_row[e]], 1);
    __syncthreads();
    sh[t] = (t < 128) ? cnt[t] : 0;
    __syncthreads();
    #pragma unroll
    for (int off = 1; off < 256; off <<= 1) {
        int v = (t >= off) ? sh[t - off] : 0;
        __syncthreads();
        sh[t] += v;
        __syncthreads();
    }
    if (t < 128) {
        int excl = (t == 0) ? 0 : sh[t - 1];
        nxt[t] = base + excl;
        int row = k * 128 + t;
        if (row < N_NODES) rowptr[row] = base + excl;
    }
    if (k == NBUK - 1 && t == 255) rowptr[N_NODES] = NE;
    __syncthreads();
    for (int e = base + t; e < end; e += 256) {
        int pos = atomicAdd(&nxt[tmp_row[e]], 1);
        pairs[pos] = tmp_pay[e];
    }
}

// ===========================================================================
// cvt: fp32 -> fp16 (RNE), n4 = element count / 4
// ===========================================================================
__global__ __launch_bounds__(256) void cvt_f2h_kernel(
    const float* __restrict__ in, unsigned short* __restrict__ out, int n4)
{
    int i = blockIdx.x * 256 + threadIdx.x;
    if (i >= n4) return;
    float4 v = ((const float4*)in)[i];
    ushort4 o;
    o.x = f2h(v.x); o.y = f2h(v.y); o.z = f2h(v.z); o.w = f2h(v.w);
    ((ushort4*)out)[i] = o;
}

// ===========================================================================
// SpMM row core (r15 best-measured form): packed 4B edges, fp16 gather
// (32 lanes x 8B), fp32 accumulate, fp16 store; 4-way unrolled.
// ===========================================================================
__device__ __forceinline__ void spmm_row(
    const unsigned short* __restrict__ xh, const unsigned* __restrict__ pairs,
    int start, int end, int sub, bool do_abs,
    unsigned short* __restrict__ yrow)
{
    const ushort4* x4 = (const ushort4*)xh + sub;  // row stride = 32 ushort4

    float4 a0 = {0,0,0,0}, a1 = {0,0,0,0};
    float4 a2 = {0,0,0,0}, a3 = {0,0,0,0};

    #define EDGE_P(P, A) { \
        unsigned _p = (P); \
        float _v = h2f((unsigned short)(_p & 0xFFFFu)); \
        ushort4 _x = x4[(size_t)(_p >> 16) * 32]; \
        A.x += _v * h2f(_x.x); \
        A.y += _v * h2f(_x.y); \
        A.z += _v * h2f(_x.z); \
        A.w += _v * h2f(_x.w); }

    int e = start;
    for (; e + 3 < end; e += 4) {
        unsigned p0 = pairs[e];
        unsigned p1 = pairs[e + 1];
        unsigned p2 = pairs[e + 2];
        unsigned p3 = pairs[e + 3];
        EDGE_P(p0, a0); EDGE_P(p1, a1); EDGE_P(p2, a2); EDGE_P(p3, a3);
    }
    for (; e < end; ++e) {
        EDGE_P(pairs[e], a0);
    }
    #undef EDGE_P

    float4 acc;
    acc.x = (a0.x + a1.x) + (a2.x + a3.x);
    acc.y = (a0.y + a1.y) + (a2.y + a3.y);
    acc.z = (a0.z + a1.z) + (a2.z + a3.z);
    acc.w = (a0.w + a1.w) + (a2.w + a3.w);
    if (do_abs) {
        acc.x = fabsf(acc.x); acc.y = fabsf(acc.y);
        acc.z = fabsf(acc.z); acc.w = fabsf(acc.w);
    }
    ushort4 o;
    o.x = f2h(acc.x); o.y = f2h(acc.y); o.z = f2h(acc.z); o.w = f2h(acc.w);
    ((ushort4*)yrow)[sub] = o;
}

// ===========================================================================
// Fused first-hop SpMM: 4 operators (A, P1, P2, P3), all gathering Xh.
// bid & 3 = op (adjacent blocks = different ops -> L2 temporal reuse of Xh).
// ===========================================================================
__global__ __launch_bounds__(256) void spmm4_kernel(
    const int* __restrict__ ptr4, const unsigned* __restrict__ pairs4,
    const unsigned short* __restrict__ Xh, unsigned short* __restrict__ B16)
{
    int bid = blockIdx.x;
    int op  = bid & 3;
    int rb  = bid >> 2;
    int r   = rb * 8 + (threadIdx.x >> 5);
    int sub = threadIdx.x & 31;
    if (r >= N_NODES) return;

    const int*      ptr   = ptr4 + (size_t)op * PTRW;
    const unsigned* pairs = pairs4 + (size_t)op * NE;
    int dst = op ? op + 2 : 0;
    unsigned short* yrow = B16 + (size_t)dst * NH + (size_t)r * HID;

    spmm_row(Xh, pairs, ptr[r], ptr[r + 1], sub, op != 0, yrow);
}

// ===========================================================================
// Chain-hop SpMM (A's CSR, no abs): src16 -> dst16.
// ===========================================================================
__global__ __launch_bounds__(256) void spmm_chain_kernel(
    const int* __restrict__ ptr, const unsigned* __restrict__ pairs,
    const unsigned short* __restrict__ src16, unsigned short* __restrict__ dst16)
{
    int t   = blockIdx.x * 256 + threadIdx.x;
    int r   = t >> 5;
    int sub = t & 31;
    if (r >= N_NODES) return;
    spmm_row(src16, pairs, ptr[r], ptr[r + 1], sub, false,
             dst16 + (size_t)r * HID);
}

// ===========================================================================
// Attention. For n < N/2 the pair is branch-independent -> softmax is
// EXACTLY uniform: att = 1/6 (no read needed). Upper half computes
// e[b] = dot(relu(B_b rows 2n-N, 2n+1-N), a) with a wave reduce.
// ===========================================================================
__global__ __launch_bounds__(256) void attn_kernel(
    const unsigned short* __restrict__ B16,
    const float* __restrict__ a, float* __restrict__ att)
{
    int wid  = (blockIdx.x * 256 + threadIdx.x) >> 6;
    int lane = threadIdx.x & 63;
    if (wid >= N_NODES) return;

    if (wid < N_NODES / 2) {
        if (lane < 6) att[(size_t)wid * 6 + lane] = 1.0f / 6.0f;
        return;
    }

    const float4 av = ((const float4*)a)[lane];
    float e[6];
    int m = 2 * wid - N_NODES;
    #pragma unroll
    for (int b = 0; b < 6; ++b) {
        ushort4 u = ((const ushort4*)(B16 + (size_t)b * NH +
                                      (size_t)m * HID))[lane];
        float s = fmaxf(h2f(u.x), 0.f) * av.x + fmaxf(h2f(u.y), 0.f) * av.y +
                  fmaxf(h2f(u.z), 0.f) * av.z + fmaxf(h2f(u.w), 0.f) * av.w;
        #pragma unroll
        for (int k = 1; k < 64; k <<= 1) s += __shfl_xor(s, k);
        e[b] = s;
    }

    if (lane == 0) {
        float mx = e[0];
        #pragma unroll
        for (int b = 1; b < 6; ++b) mx = fmaxf(mx, e[b]);
        float ex[6], sum = 0.f;
        #pragma unroll
        for (int b = 0; b < 6; ++b) { ex[b] = expf(e[b] - mx); sum += ex[b]; }
        float inv = 1.f / sum;
        #pragma unroll
        for (int b = 0; b < 6; ++b) att[(size_t)wid * 6 + b] = ex[b] * inv;
    }
}

// ===========================================================================
// Fused tail: hprime -> LDS, MFMA FC1 -> LDS, MFMA FC2 -> d_out.
// ===========================================================================
__global__ __launch_bounds__(256) void tail_kernel(
    const unsigned short* __restrict__ B16, const float* __restrict__ att,
    const unsigned short* __restrict__ Wh1, const float* __restrict__ b1,
    const unsigned short* __restrict__ Wh2, const float* __restrict__ b2,
    float* __restrict__ outp)
{
    __shared__ __align__(16) unsigned short hp[TROWS][TPAD];
    __shared__ __align__(16) unsigned short md[TROWS][TPAD];
    __shared__ float att_l[TROWS * 6];

    const int t  = threadIdx.x;
    const int n0 = blockIdx.x * TROWS;

    for (int i = t; i < TROWS * 6; i += 256)
        att_l[i] = att[min((size_t)n0 * 6 + i, (size_t)N_NODES * 6 - 1)];
    __syncthreads();

    // ---- phase 1: hprime -> hp LDS ----
    #pragma unroll 2
    for (int i = 0; i < (TROWS * HID) / 256; ++i) {
        int idx = i * 256 + t;
        int rl = idx >> 7, q = idx & 127;
        int n = min(n0 + rl, N_NODES - 1);
        float s = 0.f;
        #pragma unroll
        for (int p = 0; p < 6; ++p) {
            int f = p * HID + q;
            int j = f % 6;
            int ii = f / 6;
            s += att_l[rl * 6 + p] *
                 h2f(B16[(size_t)j * NH + (size_t)n * HID + ii]);
        }
        hp[rl][q] = f2h(s * (1.0f / 6.0f));
    }
    __syncthreads();

    const int lane = t & 63;
    const int wv   = t >> 6;
    const int lr   = lane & 15;
    const int kg   = lane >> 4;

    // ---- phase 2: FC1 hp(LDS) x W1 -> md(LDS) ----
    #pragma unroll
    for (int ci = 0; ci < 2; ++ci) {
        int cb = wv * 2 + ci;
        int o  = cb * 16 + lr;
        f16x8 bf[4];
        #pragma unroll
        for (int ks = 0; ks < 4; ++ks)
            bf[ks] = *(const f16x8*)(Wh1 + (size_t)o * HID + ks * 32 + kg * 8);
        float bo = b1[o];
        #pragma unroll
        for (int rt = 0; rt < 8; ++rt) {
            f32x4 acc = {0.f, 0.f, 0.f, 0.f};
            #pragma unroll
            for (int ks = 0; ks < 4; ++ks) {
                f16x8 af = *(const f16x8*)&hp[rt * 16 + lr][ks * 32 + kg * 8];
                acc = __builtin_amdgcn_mfma_f32_16x16x32_f16(af, bf[ks], acc,
                                                             0, 0, 0);
            }
            #pragma unroll
            for (int j = 0; j < 4; ++j) {
                float v = acc[j] + bo;
                v = v > 0.f ? v : 0.01f * v;
                md[rt * 16 + kg * 4 + j][o] = f2h(v);
            }
        }
    }
    __syncthreads();

    // ---- phase 3: FC2 md(LDS) x W2 -> global out ----
    #pragma unroll
    for (int ci = 0; ci < 2; ++ci) {
        int cb = wv * 2 + ci;
        int o  = cb * 16 + lr;
        f16x8 bf[4];
        #pragma unroll
        for (int ks = 0; ks < 4; ++ks)
            bf[ks] = *(const f16x8*)(Wh2 + (size_t)o * HID + ks * 32 + kg * 8);
        float bo = b2[o];
        #pragma unroll
        for (int rt = 0; rt < 8; ++rt) {
            f32x4 acc = {0.f, 0.f, 0.f, 0.f};
            #pragma unroll
            for (int ks = 0; ks < 4; ++ks) {
                f16x8 af = *(const f16x8*)&md[rt * 16 + lr][ks * 32 + kg * 8];
                acc = __builtin_amdgcn_mfma_f32_16x16x32_f16(af, bf[ks], acc,
                                                             0, 0, 0);
            }
            #pragma unroll
            for (int j = 0; j < 4; ++j) {
                int n = n0 + rt * 16 + kg * 4 + j;
                if (n < N_NODES) {
                    float v = acc[j] + bo;
                    v = v > 0.f ? v : 0.01f * v;
                    outp[(size_t)n * HID + o] = v;
                }
            }
        }
    }
}

// ===========================================================================
extern "C" void kernel_launch(void* const* d_in, const int* in_sizes, int n_in,
                              void* d_out, int out_size, void* d_ws, size_t ws_size,
                              hipStream_t stream)
{
    const float* X  = (const float*)d_in[0];
    const float* a  = (const float*)d_in[1];
    const float* W1 = (const float*)d_in[2];
    const float* b1 = (const float*)d_in[3];
    const float* W2 = (const float*)d_in[4];
    const float* b2 = (const float*)d_in[5];
    const int*   op_rows[4] = { (const int*)d_in[6],  (const int*)d_in[9],
                                (const int*)d_in[12], (const int*)d_in[15] };
    const int*   op_cols[4] = { (const int*)d_in[7],  (const int*)d_in[10],
                                (const int*)d_in[13], (const int*)d_in[16] };
    const float* op_vals[4] = { (const float*)d_in[8],  (const float*)d_in[11],
                                (const float*)d_in[14], (const float*)d_in[17] };
    // d_in[18..20] = Psct (unused: withgres=False)

    // ---- workspace layout (4-byte words); ~150 MB total ----
    float* ws = (float*)d_ws;
    size_t off = 0;
    unsigned short* B16 = (unsigned short*)(ws + off);  off += (size_t)6 * NH / 2;
    float* att = ws + off;                              off += (size_t)6 * N_NODES;
    unsigned short* Xh  = (unsigned short*)(ws + off);  off += NH / 2;
    unsigned short* Wh1 = (unsigned short*)(ws + off);  off += HID * HID / 2;
    unsigned short* Wh2 = (unsigned short*)(ws + off);  off += HID * HID / 2;
    int*   ptr4   = (int*)(ws + off);                   off += (size_t)4 * PTRW;
    int*   table4 = (int*)(ws + off);                   off += (size_t)4 * TBL;
    int*   part4  = (int*)(ws + off);                   off += 4 * SB + 8;
    unsigned char* tmp_row4 = (unsigned char*)(ws + off); off += (size_t)NE; // 4*NE bytes
    off = (off + 3) & ~(size_t)3;                       // 16B align
    unsigned* tmp_pay4 = (unsigned*)(ws + off);         off += (size_t)4 * NE;
    unsigned* pairs4   = (unsigned*)(ws + off);         off += (size_t)4 * NE;

    dim3 blk(256);
    const int rg = (N_NODES * 32 + 255) / 256;  // 6250 (32 lanes/row)
    const int cg = (NH / 4 + 255) / 256;        // 6250
    const int wg = (HID * HID / 4 + 255) / 256; // 16
    const int tg = (N_NODES + TROWS - 1) / TROWS; // 391

    // ---- conversions ----
    cvt_f2h_kernel<<<cg, blk, 0, stream>>>(X, Xh, NH / 4);
    cvt_f2h_kernel<<<wg, blk, 0, stream>>>(W1, Wh1, HID * HID / 4);
    cvt_f2h_kernel<<<wg, blk, 0, stream>>>(W2, Wh2, HID * HID / 4);

    // ---- batched counting-sort: 6 dispatches for all 4 operators ----
    k1_hist4<<<dim3(NBLK1, 4), blk, 0, stream>>>(
        op_rows[0], op_rows[1], op_rows[2], op_rows[3], table4);
    s1_partial4<<<dim3(SB, 4), blk, 0, stream>>>(table4, part4);
    s2_scan4<<<4, 1024, 0, stream>>>(part4);
    s3_add4<<<dim3(SB, 4), blk, 0, stream>>>(table4, part4);
    k3_scatter4<<<dim3(NBLK1, 4), blk, 0, stream>>>(
        op_rows[0], op_rows[1], op_rows[2], op_rows[3],
        op_cols[0], op_cols[1], op_cols[2], op_cols[3],
        op_vals[0], op_vals[1], op_vals[2], op_vals[3],
        table4, tmp_row4, tmp_pay4);
    k4_fine4<<<dim3(NBUK, 4), blk, 0, stream>>>(table4, tmp_row4, tmp_pay4,
                                                pairs4, ptr4);

    // ---- fused first-hop spmm (A,P1,P2,P3 all gather Xh; L2 reuse) ----
    spmm4_kernel<<<rg * 4, blk, 0, stream>>>(ptr4, pairs4, Xh, B16);

    // ---- chain hops 2,3 (A's CSR; fp16 in/out) ----
    spmm_chain_kernel<<<rg, blk, 0, stream>>>(ptr4, pairs4,
                                              B16 + 0 * (size_t)NH,
                                              B16 + 1 * (size_t)NH);
    spmm_chain_kernel<<<rg, blk, 0, stream>>>(ptr4, pairs4,
                                              B16 + 1 * (size_t)NH,
                                              B16 + 2 * (size_t)NH);

    // ---- attention (upper half only; lower = exact 1/6), fused tail ----
    attn_kernel<<<(N_NODES + 3) / 4, blk, 0, stream>>>(B16, a, att);
    tail_kernel<<<tg, blk, 0, stream>>>(B16, att, Wh1, b1, Wh2, b2,
                                        (float*)d_out);
}

// Round 18
// 590.457 us; speedup vs baseline: 1.1612x; 1.1612x over previous
//
#include <hip/hip_runtime.h>
#include <hip/hip_fp16.h>

#define N_NODES 50000
#define HID 128
#define NH (N_NODES * HID)      // 6,400,000 elems per [N,HID] buffer
#define NE 1600000

#define EPB   8192              // edges per K1/K3 block
#define NBLK1 196               // ceil(NE / EPB)
#define NBUK  391               // ceil(N_NODES / 128) row buckets (128 rows each)
#define TBL   (NBUK * NBLK1)    // 76,636 scan table entries per op
#define SB    ((TBL + 255) / 256)  // 300 scan blocks per op
#define PTRW  (N_NODES + 2)     // words per rowptr array

#define TROWS 128               // rows per tail block
#define TPAD  136               // fp16 row pitch in LDS

typedef _Float16 f16x8 __attribute__((ext_vector_type(8)));
typedef float    f32x4 __attribute__((ext_vector_type(4)));

// ---- fp16 helpers (RNE) ----
__device__ __forceinline__ float h2f(unsigned short u) {
    __half_raw r; r.x = u;
    __half h = r;
    return __half2float(h);
}
__device__ __forceinline__ unsigned short f2h(float f) {
    __half h = __float2half_rn(f);
    __half_raw r = h;
    return r.x;
}
__device__ __forceinline__ float h2f_lo(unsigned u) { return h2f((unsigned short)(u & 0xFFFFu)); }
__device__ __forceinline__ float h2f_hi(unsigned u) { return h2f((unsigned short)(u >> 16)); }

// ===========================================================================
// K1 (batched 4 ops): per-block LDS histogram + per-edge rank.
// NOTE: rank is not overhead — k3's write coalescing depends on it (r17).
// ===========================================================================
__global__ __launch_bounds__(256) void k1_hist4(
    const int* __restrict__ r0, const int* __restrict__ r1,
    const int* __restrict__ r2, const int* __restrict__ r3,
    int* __restrict__ table4, unsigned short* __restrict__ rank4)
{
    __shared__ int h[NBUK];
    int o = blockIdx.y, b = blockIdx.x, t = threadIdx.x;
    const int* rows = o == 0 ? r0 : o == 1 ? r1 : o == 2 ? r2 : r3;
    int* table = table4 + (size_t)o * TBL;
    unsigned short* rank = rank4 + (size_t)o * NE;

    for (int i = t; i < NBUK; i += 256) h[i] = 0;
    __syncthreads();
    int e0 = b * EPB;
    int e1 = min(e0 + EPB, NE);
    for (int e = e0 + t; e < e1; e += 256)
        rank[e] = (unsigned short)atomicAdd(&h[rows[e] >> 7], 1);
    __syncthreads();
    for (int i = t; i < NBUK; i += 256) table[i * NBLK1 + b] = h[i];
}

// ===========================================================================
// S1/S2/S3 (batched): hierarchical exclusive scan of each op's table
// ===========================================================================
__global__ __launch_bounds__(256) void s1_partial4(
    const int* __restrict__ table4, int* __restrict__ part4)
{
    __shared__ int red[256];
    int o = blockIdx.y, b = blockIdx.x, t = threadIdx.x;
    const int* table = table4 + (size_t)o * TBL;
    int idx = b * 256 + t;
    red[t] = (idx < TBL) ? table[idx] : 0;
    __syncthreads();
    #pragma unroll
    for (int s = 128; s > 0; s >>= 1) {
        if (t < s) red[t] += red[t + s];
        __syncthreads();
    }
    if (t == 0) part4[o * SB + b] = red[0];
}

__global__ __launch_bounds__(1024) void s2_scan4(int* __restrict__ part4)
{
    __shared__ int sh[1024];
    int o = blockIdx.x, t = threadIdx.x;
    int* part = part4 + o * SB;
    sh[t] = (t < SB) ? part[t] : 0;
    __syncthreads();
    for (int off = 1; off < 1024; off <<= 1) {
        int v = (t >= off) ? sh[t - off] : 0;
        __syncthreads();
        sh[t] += v;
        __syncthreads();
    }
    if (t < SB) part[t] = (t == 0) ? 0 : sh[t - 1];
}

__global__ __launch_bounds__(256) void s3_add4(
    int* __restrict__ table4, const int* __restrict__ part4)
{
    __shared__ int sh[256];
    int o = blockIdx.y, b = blockIdx.x, t = threadIdx.x;
    int* table = table4 + (size_t)o * TBL;
    int idx = b * 256 + t;
    int v = (idx < TBL) ? table[idx] : 0;
    sh[t] = v;
    __syncthreads();
    #pragma unroll
    for (int off = 1; off < 256; off <<= 1) {
        int u = (t >= off) ? sh[t - off] : 0;
        __syncthreads();
        sh[t] += u;
        __syncthreads();
    }
    int excl = (t == 0) ? 0 : sh[t - 1];
    if (idx < TBL) table[idx] = part4[o * SB + b] + excl;
}

// ===========================================================================
// K3 (batched): atomic-free scatter into bucket-partitioned tmp.
// tmp entry: .x = row&127, .y = col<<16 | fp16(val)
// ===========================================================================
__global__ __launch_bounds__(256) void k3_scatter4(
    const int* __restrict__ r0, const int* __restrict__ r1,
    const int* __restrict__ r2, const int* __restrict__ r3,
    const int* __restrict__ c0, const int* __restrict__ c1,
    const int* __restrict__ c2, const int* __restrict__ c3,
    const float* __restrict__ v0, const float* __restrict__ v1,
    const float* __restrict__ v2, const float* __restrict__ v3,
    const unsigned short* __restrict__ rank4,
    const int* __restrict__ table4, int2* __restrict__ tmp4)
{
    __shared__ int base[NBUK];
    int o = blockIdx.y, b = blockIdx.x, t = threadIdx.x;
    const int*   rows = o == 0 ? r0 : o == 1 ? r1 : o == 2 ? r2 : r3;
    const int*   cols = o == 0 ? c0 : o == 1 ? c1 : o == 2 ? c2 : c3;
    const float* vals = o == 0 ? v0 : o == 1 ? v1 : o == 2 ? v2 : v3;
    const int* table = table4 + (size_t)o * TBL;
    const unsigned short* rank = rank4 + (size_t)o * NE;
    int2* tmp = tmp4 + (size_t)o * NE;

    for (int i = t; i < NBUK; i += 256) base[i] = table[i * NBLK1 + b];
    __syncthreads();
    int e0 = b * EPB;
    int e1 = min(e0 + EPB, NE);
    for (int e = e0 + t; e < e1; e += 256) {
        int r = rows[e];
        int pos = base[r >> 7] + (int)rank[e];
        unsigned pk = ((unsigned)cols[e] << 16) | (unsigned)f2h(vals[e]);
        tmp[pos] = make_int2(r & 127, (int)pk);
    }
}

// ===========================================================================
// K4 (batched): per-bucket fine sort -> packed pairs (4B) + rowptr.
// ===========================================================================
__global__ __launch_bounds__(256) void k4_fine4(
    const int* __restrict__ table4, const int2* __restrict__ tmp4,
    unsigned* __restrict__ pairs4, int* __restrict__ ptr4)
{
    __shared__ int cnt[128];
    __shared__ int sh[256];
    __shared__ int nxt[128];
    int o = blockIdx.y, k = blockIdx.x, t = threadIdx.x;
    const int* table = table4 + (size_t)o * TBL;
    const int2* tmp = tmp4 + (size_t)o * NE;
    unsigned* pairs = pairs4 + (size_t)o * NE;
    int* rowptr = ptr4 + (size_t)o * PTRW;

    if (t < 128) cnt[t] = 0;
    __syncthreads();
    int base = table[k * NBLK1];
    int end  = (k == NBUK - 1) ? NE : table[(k + 1) * NBLK1];
    for (int e = base + t; e < end; e += 256)
        atomicAdd(&cnt[tmp[e].x], 1);
    __syncthreads();
    sh[t] = (t < 128) ? cnt[t] : 0;
    __syncthreads();
    #pragma unroll
    for (int off = 1; off < 256; off <<= 1) {
        int v = (t >= off) ? sh[t - off] : 0;
        __syncthreads();
        sh[t] += v;
        __syncthreads();
    }
    if (t < 128) {
        int excl = (t == 0) ? 0 : sh[t - 1];
        nxt[t] = base + excl;
        int row = k * 128 + t;
        if (row < N_NODES) rowptr[row] = base + excl;
    }
    if (k == NBUK - 1 && t == 255) rowptr[N_NODES] = NE;
    __syncthreads();
    for (int e = base + t; e < end; e += 256) {
        int2 p = tmp[e];
        int pos = atomicAdd(&nxt[p.x], 1);
        pairs[pos] = (unsigned)p.y;
    }
}

// ===========================================================================
// cvt: fp32 -> fp16 (RNE), n4 = element count / 4
// ===========================================================================
__global__ __launch_bounds__(256) void cvt_f2h_kernel(
    const float* __restrict__ in, unsigned short* __restrict__ out, int n4)
{
    int i = blockIdx.x * 256 + threadIdx.x;
    if (i >= n4) return;
    float4 v = ((const float4*)in)[i];
    ushort4 o;
    o.x = f2h(v.x); o.y = f2h(v.y); o.z = f2h(v.z); o.w = f2h(v.w);
    ((ushort4*)out)[i] = o;
}

// ===========================================================================
// SpMM row core (16-lane): packed 4B edges, 16B gathers (uint4 = 8 fp16),
// fp32 accumulate, fp16 store.
// ===========================================================================
__device__ __forceinline__ void spmm_row16(
    const unsigned short* __restrict__ xh, const unsigned* __restrict__ pairs,
    int start, int end, int sub, bool do_abs,
    unsigned short* __restrict__ yrow)
{
    const uint4* x8 = (const uint4*)xh + sub;   // row stride = 16 uint4 (256B)

    float4 a0 = {0,0,0,0}, a1 = {0,0,0,0};
    float4 c0 = {0,0,0,0}, c1 = {0,0,0,0};

    #define EDGE16(XV, V, A0, A1) { \
        A0.x += (V) * h2f_lo(XV.x); A0.y += (V) * h2f_hi(XV.x); \
        A0.z += (V) * h2f_lo(XV.y); A0.w += (V) * h2f_hi(XV.y); \
        A1.x += (V) * h2f_lo(XV.z); A1.y += (V) * h2f_hi(XV.z); \
        A1.z += (V) * h2f_lo(XV.w); A1.w += (V) * h2f_hi(XV.w); }

    int e = start;
    for (; e + 3 < end; e += 4) {
        unsigned p0 = pairs[e];
        unsigned p1 = pairs[e + 1];
        unsigned p2 = pairs[e + 2];
        unsigned p3 = pairs[e + 3];
        uint4 x0 = x8[(size_t)(p0 >> 16) * 16];
        uint4 x1 = x8[(size_t)(p1 >> 16) * 16];
        uint4 x2 = x8[(size_t)(p2 >> 16) * 16];
        uint4 x3 = x8[(size_t)(p3 >> 16) * 16];
        float v0 = h2f((unsigned short)(p0 & 0xFFFFu));
        float v1 = h2f((unsigned short)(p1 & 0xFFFFu));
        float v2 = h2f((unsigned short)(p2 & 0xFFFFu));
        float v3 = h2f((unsigned short)(p3 & 0xFFFFu));
        EDGE16(x0, v0, a0, a1); EDGE16(x1, v1, c0, c1);
        EDGE16(x2, v2, a0, a1); EDGE16(x3, v3, c0, c1);
    }
    for (; e < end; ++e) {
        unsigned p0 = pairs[e];
        uint4 x0 = x8[(size_t)(p0 >> 16) * 16];
        float v0 = h2f((unsigned short)(p0 & 0xFFFFu));
        EDGE16(x0, v0, a0, a1);
    }
    #undef EDGE16

    a0.x += c0.x; a0.y += c0.y; a0.z += c0.z; a0.w += c0.w;
    a1.x += c1.x; a1.y += c1.y; a1.z += c1.z; a1.w += c1.w;
    if (do_abs) {
        a0.x = fabsf(a0.x); a0.y = fabsf(a0.y); a0.z = fabsf(a0.z); a0.w = fabsf(a0.w);
        a1.x = fabsf(a1.x); a1.y = fabsf(a1.y); a1.z = fabsf(a1.z); a1.w = fabsf(a1.w);
    }
    uint4 o;
    o.x = (unsigned)f2h(a0.x) | ((unsigned)f2h(a0.y) << 16);
    o.y = (unsigned)f2h(a0.z) | ((unsigned)f2h(a0.w) << 16);
    o.z = (unsigned)f2h(a1.x) | ((unsigned)f2h(a1.y) << 16);
    o.w = (unsigned)f2h(a1.z) | ((unsigned)f2h(a1.w) << 16);
    ((uint4*)yrow)[sub] = o;
}

// ===========================================================================
// Fused first-hop SpMM: 4 operators (A, P1, P2, P3), all gathering Xh.
// bid & 3 = op (adjacent blocks = different ops -> L2 temporal reuse of Xh).
// ===========================================================================
__global__ __launch_bounds__(256) void spmm4_kernel(
    const int* __restrict__ ptr4, const unsigned* __restrict__ pairs4,
    const unsigned short* __restrict__ Xh, unsigned short* __restrict__ B16)
{
    int bid = blockIdx.x;
    int op  = bid & 3;
    int rb  = bid >> 2;
    int r   = rb * 16 + (threadIdx.x >> 4);
    int sub = threadIdx.x & 15;
    if (r >= N_NODES) return;

    const int*      ptr   = ptr4 + (size_t)op * PTRW;
    const unsigned* pairs = pairs4 + (size_t)op * NE;
    int dst = op ? op + 2 : 0;
    unsigned short* yrow = B16 + (size_t)dst * NH + (size_t)r * HID;

    spmm_row16(Xh, pairs, ptr[r], ptr[r + 1], sub, op != 0, yrow);
}

// ===========================================================================
// Chain-hop SpMM (A's CSR, no abs): src16 -> dst16.
// ===========================================================================
__global__ __launch_bounds__(256) void spmm_chain_kernel(
    const int* __restrict__ ptr, const unsigned* __restrict__ pairs,
    const unsigned short* __restrict__ src16, unsigned short* __restrict__ dst16)
{
    int t   = blockIdx.x * 256 + threadIdx.x;
    int r   = t >> 4;
    int sub = t & 15;
    if (r >= N_NODES) return;
    spmm_row16(src16, pairs, ptr[r], ptr[r + 1], sub, false,
               dst16 + (size_t)r * HID);
}

// ===========================================================================
// Attention. For n < N/2 the pair is branch-independent -> softmax is
// EXACTLY uniform: att = 1/6 (no read needed).
// ===========================================================================
__global__ __launch_bounds__(256) void attn_kernel(
    const unsigned short* __restrict__ B16,
    const float* __restrict__ a, float* __restrict__ att)
{
    int wid  = (blockIdx.x * 256 + threadIdx.x) >> 6;
    int lane = threadIdx.x & 63;
    if (wid >= N_NODES) return;

    if (wid < N_NODES / 2) {
        if (lane < 6) att[(size_t)wid * 6 + lane] = 1.0f / 6.0f;
        return;
    }

    const float4 av = ((const float4*)a)[lane];
    float e[6];
    int m = 2 * wid - N_NODES;
    #pragma unroll
    for (int b = 0; b < 6; ++b) {
        ushort4 u = ((const ushort4*)(B16 + (size_t)b * NH +
                                      (size_t)m * HID))[lane];
        float s = fmaxf(h2f(u.x), 0.f) * av.x + fmaxf(h2f(u.y), 0.f) * av.y +
                  fmaxf(h2f(u.z), 0.f) * av.z + fmaxf(h2f(u.w), 0.f) * av.w;
        #pragma unroll
        for (int k = 1; k < 64; k <<= 1) s += __shfl_xor(s, k);
        e[b] = s;
    }

    if (lane == 0) {
        float mx = e[0];
        #pragma unroll
        for (int b = 1; b < 6; ++b) mx = fmaxf(mx, e[b]);
        float ex[6], sum = 0.f;
        #pragma unroll
        for (int b = 0; b < 6; ++b) { ex[b] = expf(e[b] - mx); sum += ex[b]; }
        float inv = 1.f / sum;
        #pragma unroll
        for (int b = 0; b < 6; ++b) att[(size_t)wid * 6 + b] = ex[b] * inv;
    }
}

// ===========================================================================
// Fused tail: hprime -> LDS, MFMA FC1 -> LDS, MFMA FC2 -> d_out.
// ===========================================================================
__global__ __launch_bounds__(256) void tail_kernel(
    const unsigned short* __restrict__ B16, const float* __restrict__ att,
    const unsigned short* __restrict__ Wh1, const float* __restrict__ b1,
    const unsigned short* __restrict__ Wh2, const float* __restrict__ b2,
    float* __restrict__ outp)
{
    __shared__ __align__(16) unsigned short hp[TROWS][TPAD];
    __shared__ __align__(16) unsigned short md[TROWS][TPAD];
    __shared__ float att_l[TROWS * 6];

    const int t  = threadIdx.x;
    const int n0 = blockIdx.x * TROWS;

    for (int i = t; i < TROWS * 6; i += 256)
        att_l[i] = att[min((size_t)n0 * 6 + i, (size_t)N_NODES * 6 - 1)];
    __syncthreads();

    // ---- phase 1: hprime -> hp LDS ----
    #pragma unroll 2
    for (int i = 0; i < (TROWS * HID) / 256; ++i) {
        int idx = i * 256 + t;
        int rl = idx >> 7, q = idx & 127;
        int n = min(n0 + rl, N_NODES - 1);
        float s = 0.f;
        #pragma unroll
        for (int p = 0; p < 6; ++p) {
            int f = p * HID + q;
            int j = f % 6;
            int ii = f / 6;
            s += att_l[rl * 6 + p] *
                 h2f(B16[(size_t)j * NH + (size_t)n * HID + ii]);
        }
        hp[rl][q] = f2h(s * (1.0f / 6.0f));
    }
    __syncthreads();

    const int lane = t & 63;
    const int wv   = t >> 6;
    const int lr   = lane & 15;
    const int kg   = lane >> 4;

    // ---- phase 2: FC1 hp(LDS) x W1 -> md(LDS) ----
    #pragma unroll
    for (int ci = 0; ci < 2; ++ci) {
        int cb = wv * 2 + ci;
        int o  = cb * 16 + lr;
        f16x8 bf[4];
        #pragma unroll
        for (int ks = 0; ks < 4; ++ks)
            bf[ks] = *(const f16x8*)(Wh1 + (size_t)o * HID + ks * 32 + kg * 8);
        float bo = b1[o];
        #pragma unroll
        for (int rt = 0; rt < 8; ++rt) {
            f32x4 acc = {0.f, 0.f, 0.f, 0.f};
            #pragma unroll
            for (int ks = 0; ks < 4; ++ks) {
                f16x8 af = *(const f16x8*)&hp[rt * 16 + lr][ks * 32 + kg * 8];
                acc = __builtin_amdgcn_mfma_f32_16x16x32_f16(af, bf[ks], acc,
                                                             0, 0, 0);
            }
            #pragma unroll
            for (int j = 0; j < 4; ++j) {
                float v = acc[j] + bo;
                v = v > 0.f ? v : 0.01f * v;
                md[rt * 16 + kg * 4 + j][o] = f2h(v);
            }
        }
    }
    __syncthreads();

    // ---- phase 3: FC2 md(LDS) x W2 -> global out ----
    #pragma unroll
    for (int ci = 0; ci < 2; ++ci) {
        int cb = wv * 2 + ci;
        int o  = cb * 16 + lr;
        f16x8 bf[4];
        #pragma unroll
        for (int ks = 0; ks < 4; ++ks)
            bf[ks] = *(const f16x8*)(Wh2 + (size_t)o * HID + ks * 32 + kg * 8);
        float bo = b2[o];
        #pragma unroll
        for (int rt = 0; rt < 8; ++rt) {
            f32x4 acc = {0.f, 0.f, 0.f, 0.f};
            #pragma unroll
            for (int ks = 0; ks < 4; ++ks) {
                f16x8 af = *(const f16x8*)&md[rt * 16 + lr][ks * 32 + kg * 8];
                acc = __builtin_amdgcn_mfma_f32_16x16x32_f16(af, bf[ks], acc,
                                                             0, 0, 0);
            }
            #pragma unroll
            for (int j = 0; j < 4; ++j) {
                int n = n0 + rt * 16 + kg * 4 + j;
                if (n < N_NODES) {
                    float v = acc[j] + bo;
                    v = v > 0.f ? v : 0.01f * v;
                    outp[(size_t)n * HID + o] = v;
                }
            }
        }
    }
}

// ===========================================================================
extern "C" void kernel_launch(void* const* d_in, const int* in_sizes, int n_in,
                              void* d_out, int out_size, void* d_ws, size_t ws_size,
                              hipStream_t stream)
{
    const float* X  = (const float*)d_in[0];
    const float* a  = (const float*)d_in[1];
    const float* W1 = (const float*)d_in[2];
    const float* b1 = (const float*)d_in[3];
    const float* W2 = (const float*)d_in[4];
    const float* b2 = (const float*)d_in[5];
    const int*   op_rows[4] = { (const int*)d_in[6],  (const int*)d_in[9],
                                (const int*)d_in[12], (const int*)d_in[15] };
    const int*   op_cols[4] = { (const int*)d_in[7],  (const int*)d_in[10],
                                (const int*)d_in[13], (const int*)d_in[16] };
    const float* op_vals[4] = { (const float*)d_in[8],  (const float*)d_in[11],
                                (const float*)d_in[14], (const float*)d_in[17] };
    // d_in[18..20] = Psct (unused: withgres=False)

    // ---- workspace layout (4-byte words) ----
    float* ws = (float*)d_ws;
    size_t off = 0;
    unsigned short* B16 = (unsigned short*)(ws + off);  off += (size_t)6 * NH / 2;
    float* att = ws + off;                              off += (size_t)6 * N_NODES;
    unsigned short* Xh  = (unsigned short*)(ws + off);  off += NH / 2;
    unsigned short* Wh1 = (unsigned short*)(ws + off);  off += HID * HID / 2;
    unsigned short* Wh2 = (unsigned short*)(ws + off);  off += HID * HID / 2;
    int*   ptr4   = (int*)(ws + off);                   off += (size_t)4 * PTRW;
    int*   table4 = (int*)(ws + off);                   off += (size_t)4 * TBL;
    int*   part4  = (int*)(ws + off);                   off += 4 * SB + 8;
    unsigned short* rank4 = (unsigned short*)(ws + off); off += (size_t)4 * NE / 2;
    off = (off + 3) & ~(size_t)3;                       // 16B align
    int2*     tmp4   = (int2*)(ws + off);               off += (size_t)8 * NE;
    unsigned* pairs4 = (unsigned*)(ws + off);           off += (size_t)4 * NE;

    dim3 blk(256);
    const int rg = (N_NODES * 16 + 255) / 256;  // 3125 (16 lanes/row)
    const int cg = (NH / 4 + 255) / 256;        // 6250
    const int wg = (HID * HID / 4 + 255) / 256; // 16
    const int tg = (N_NODES + TROWS - 1) / TROWS; // 391

    // ---- conversions ----
    cvt_f2h_kernel<<<cg, blk, 0, stream>>>(X, Xh, NH / 4);
    cvt_f2h_kernel<<<wg, blk, 0, stream>>>(W1, Wh1, HID * HID / 4);
    cvt_f2h_kernel<<<wg, blk, 0, stream>>>(W2, Wh2, HID * HID / 4);

    // ---- batched counting-sort: 6 dispatches for all 4 operators ----
    k1_hist4<<<dim3(NBLK1, 4), blk, 0, stream>>>(
        op_rows[0], op_rows[1], op_rows[2], op_rows[3], table4, rank4);
    s1_partial4<<<dim3(SB, 4), blk, 0, stream>>>(table4, part4);
    s2_scan4<<<4, 1024, 0, stream>>>(part4);
    s3_add4<<<dim3(SB, 4), blk, 0, stream>>>(table4, part4);
    k3_scatter4<<<dim3(NBLK1, 4), blk, 0, stream>>>(
        op_rows[0], op_rows[1], op_rows[2], op_rows[3],
        op_cols[0], op_cols[1], op_cols[2], op_cols[3],
        op_vals[0], op_vals[1], op_vals[2], op_vals[3],
        rank4, table4, tmp4);
    k4_fine4<<<dim3(NBUK, 4), blk, 0, stream>>>(table4, tmp4, pairs4, ptr4);

    // ---- fused first-hop spmm (A,P1,P2,P3 all gather Xh; L2 reuse) ----
    spmm4_kernel<<<rg * 4, blk, 0, stream>>>(ptr4, pairs4, Xh, B16);

    // ---- chain hops 2,3 (A's CSR; fp16 in/out) ----
    spmm_chain_kernel<<<rg, blk, 0, stream>>>(ptr4, pairs4,
                                              B16 + 0 * (size_t)NH,
                                              B16 + 1 * (size_t)NH);
    spmm_chain_kernel<<<rg, blk, 0, stream>>>(ptr4, pairs4,
                                              B16 + 1 * (size_t)NH,
                                              B16 + 2 * (size_t)NH);

    // ---- attention (upper half only; lower = exact 1/6), fused tail ----
    attn_kernel<<<(N_NODES + 3) / 4, blk, 0, stream>>>(B16, a, att);
    tail_kernel<<<tg, blk, 0, stream>>>(B16, att, Wh1, b1, Wh2, b2,
                                        (float*)d_out);
}